// Round 7
// baseline (1045.726 us; speedup 1.0000x reference)
//
#include <hip/hip_runtime.h>
#include <hip/hip_bf16.h>
#include <stdint.h>

// ---------------------------------------------------------------------------
// Transformer decoder layer, bf16 MFMA pipeline.
// B=4, S=2048, D=1024, H=16, dk=64, DFF=4096, tokens=8192.
// Round 7: add gemm256 -- 256x256-tile, 8-wave, ring-of-4 LDS, counted-vmcnt
// deep pipeline (T3+T4) for the three large-N GEMMs (QKV, CAKV, FF1).
// ---------------------------------------------------------------------------

typedef __bf16 bf16_t;
typedef __bf16 bf16x8 __attribute__((ext_vector_type(8)));
typedef __bf16 bf16x4 __attribute__((ext_vector_type(4)));
typedef float  f32x4  __attribute__((ext_vector_type(4)));
typedef short  s16x4  __attribute__((ext_vector_type(4)));

#define SEQ_    2048
#define BATCH_  4
#define DM_     1024
#define NH_     16
#define DK_     64
#define DFF_    4096
#define TOK_    (BATCH_*SEQ_)     // 8192
#define BH_     (BATCH_*NH_)      // 64
#define HEADEL_ ((size_t)BH_*SEQ_*DK_)   // elements per head tensor

// 1/sqrt(dk) * log2(e): fold attention scale + exp->exp2 into Q projection
#define QSCALE_ 0.18033688011112042f

#define MFMA_BF16(a,b,c) __builtin_amdgcn_mfma_f32_16x16x32_bf16((a),(b),(c),0,0,0)
// K=16 bf16 MFMA (instruction v_mfma_f32_16x16x16_bf16)
#define MFMA16(a,b,c) __builtin_amdgcn_mfma_f32_16x16x16bf16_1k((a),(b),(c),0,0,0)

static __device__ __forceinline__ void gl_lds16(const void* g, void* l) {
  __builtin_amdgcn_global_load_lds(
      (const __attribute__((address_space(1))) uint32_t*)g,
      (__attribute__((address_space(3))) uint32_t*)l, 16, 0, 0);
}

static __device__ __forceinline__ float fast_exp2(float x) {
#if __has_builtin(__builtin_amdgcn_exp2f)
  return __builtin_amdgcn_exp2f(x);
#else
  return exp2f(x);
#endif
}

// --------------------- shared epilogue scatter helper ----------------------
// mode 0: [row*N+col]; mode 1: (B,H,S,dk); mode 2: (B,H,dk,S);
// mode 3: QKV fused (seg0 Q scaled, seg1 K, seg2 V^T); mode 4: KV fused.
static __device__ __forceinline__ void store_out(
    int mode, int relu, float scale,
    const float* bias, const float* bias2, const float* bias3,
    float* outF, bf16_t* outB, int N,
    int row, int col, float accv)
{
  float bv, sc = scale;
  int seg = 0, cw = col;
  if (mode == 3) {
    seg = col >> 10; cw = col & 1023;
    bv = (seg == 0) ? bias[cw] : ((seg == 1) ? bias2[cw] : bias3[cw]);
    if (seg != 0) sc = 1.f;
  } else if (mode == 4) {
    seg = col >> 10; cw = col & 1023;
    bv = (seg == 0) ? bias[cw] : bias2[cw];
  } else {
    bv = bias[col];
  }
  float v = (accv + bv) * sc;
  if (relu) v = fmaxf(v, 0.f);
  if (outF) outF[(size_t)row * N + col] = v;
  if (outB) {
    size_t idx;
    if (mode == 0) {
      idx = (size_t)row * N + col;
    } else {
      int bb = row >> 11, s = row & 2047, h = cw >> 6, d = cw & 63;
      bool vt; size_t base;
      if (mode == 1)      { vt = false; base = 0; }
      else if (mode == 2) { vt = true;  base = 0; }
      else if (mode == 3) { vt = (seg == 2); base = (size_t)seg * HEADEL_; }
      else                { vt = (seg == 1); base = (size_t)seg * HEADEL_; }
      if (!vt) idx = base + ((size_t)(bb * NH_ + h) * SEQ_ + s) * DK_ + d;
      else     idx = base + ((size_t)(bb * NH_ + h) * DK_ + d) * SEQ_ + s;
    }
    outB[idx] = (bf16_t)v;
  }
}

// --------------------------- f32 -> bf16 convert ---------------------------
__global__ __launch_bounds__(256) void cvt_bf16(const float* __restrict__ in,
                                                bf16_t* __restrict__ out, int n4) {
  int i = blockIdx.x * 256 + threadIdx.x;
  if (i < n4) {
    f32x4 v = *(const f32x4*)(in + (size_t)i * 4);
    bf16x4 o;
    o[0] = (bf16_t)v[0]; o[1] = (bf16_t)v[1]; o[2] = (bf16_t)v[2]; o[3] = (bf16_t)v[3];
    *(bf16x4*)(out + (size_t)i * 4) = o;
  }
}

// -------------------- weight transpose: W(K,N) -> Wt(N,K) bf16 -------------
__global__ __launch_bounds__(256) void transpose_w(const float* __restrict__ W,
                                                   bf16_t* __restrict__ Wt,
                                                   int K, int N) {
  __shared__ float t[32][33];
  int bx = blockIdx.x * 32;
  int by = blockIdx.y * 32;
  int tx = threadIdx.x;
  int ty = threadIdx.y;
  #pragma unroll
  for (int i = 0; i < 32; i += 8)
    t[ty + i][tx] = W[(size_t)(by + ty + i) * N + bx + tx];
  __syncthreads();
  #pragma unroll
  for (int i = 0; i < 32; i += 8)
    Wt[(size_t)(bx + ty + i) * K + by + tx] = (bf16_t)t[tx][ty + i];
}

// ---- batched variant: 8 square DM_ x DM_ attn weights in ONE launch -------
__global__ __launch_bounds__(256) void transpose_w8(
    const float* __restrict__ w0, const float* __restrict__ w1,
    const float* __restrict__ w2, const float* __restrict__ w3,
    const float* __restrict__ w4, const float* __restrict__ w5,
    const float* __restrict__ w6, const float* __restrict__ w7,
    bf16_t* __restrict__ dst)
{
  __shared__ float t[32][33];
  const int z = blockIdx.z;
  const float* W;
  switch (z) {
    case 0: W = w0; break; case 1: W = w1; break;
    case 2: W = w2; break; case 3: W = w3; break;
    case 4: W = w4; break; case 5: W = w5; break;
    case 6: W = w6; break; default: W = w7; break;
  }
  bf16_t* Wt = dst + (size_t)z * DM_ * DM_;
  int bx = blockIdx.x * 32;
  int by = blockIdx.y * 32;
  int tx = threadIdx.x;
  int ty = threadIdx.y;
  #pragma unroll
  for (int i = 0; i < 32; i += 8)
    t[ty + i][tx] = W[(size_t)(by + ty + i) * DM_ + bx + tx];
  __syncthreads();
  #pragma unroll
  for (int i = 0; i < 32; i += 8)
    Wt[(size_t)(bx + ty + i) * DM_ + by + tx] = (bf16_t)t[tx][ty + i];
}

// ------------------------- GEMM 128^2 (2-phase) ----------------------------
// Kept for N=1024 shapes (AO x2, CAQ, FF2). Swizzled LDS (round 6).
__global__ __launch_bounds__(256) void gemm_bf16(
    const bf16_t* __restrict__ A, const bf16_t* __restrict__ Bt,
    const float* __restrict__ bias, const float* __restrict__ bias2,
    const float* __restrict__ bias3,
    float* outF, bf16_t* outB,
    int M, int N, int K, int mode, int relu, float scale)
{
  __shared__ __attribute__((aligned(16))) bf16_t lsA[2][128 * 32];
  __shared__ __attribute__((aligned(16))) bf16_t lsB[2][128 * 32];

  const int tid  = threadIdx.x;
  const int lane = tid & 63;
  const int w    = tid >> 6;
  const int q    = lane >> 4;
  const int r    = lane & 15;

  const int gx = gridDim.x;
  const int b  = blockIdx.y * gx + blockIdx.x;
  const int t_ = b >> 3;
  const int bm = (t_ / gx) * 8 + (b & 7);
  const int bn = t_ % gx;
  const int m0 = bm * 128;
  const int n0 = bn * 128;

  const int mb   = (w >> 1) * 64;
  const int nb   = (w & 1) * 64;
  const int qs = (q ^ ((r >> 1) & 3)) * 8;

  f32x4 acc[4][4] = {};

  for (int k0 = 0; k0 < K; k0 += 64) {
    #pragma unroll
    for (int h = 0; h < 2; ++h) {
      #pragma unroll
      for (int rr = 0; rr < 2; ++rr) {
        int flat = rr * 2048 + tid * 8;
        int row  = flat >> 5;
        int col  = ((((flat >> 3) & 3) ^ ((flat >> 6) & 3)) << 3);
        gl_lds16(A  + (size_t)(m0 + row) * K + k0 + 32 * h + col, &lsA[h][flat]);
        gl_lds16(Bt + (size_t)(n0 + row) * K + k0 + 32 * h + col, &lsB[h][flat]);
      }
    }
    __syncthreads();
    #pragma unroll
    for (int h = 0; h < 2; ++h) {
      bf16x8 af[4], bfr[4];
      #pragma unroll
      for (int mi = 0; mi < 4; ++mi)
        af[mi] = *(const bf16x8*)&lsA[h][(mb + mi * 16 + r) * 32 + qs];
      #pragma unroll
      for (int ni = 0; ni < 4; ++ni)
        bfr[ni] = *(const bf16x8*)&lsB[h][(nb + ni * 16 + r) * 32 + qs];
      #pragma unroll
      for (int mi = 0; mi < 4; ++mi)
        #pragma unroll
        for (int ni = 0; ni < 4; ++ni)
          acc[mi][ni] = MFMA_BF16(af[mi], bfr[ni], acc[mi][ni]);
    }
    __syncthreads();
  }

  #pragma unroll
  for (int mi = 0; mi < 4; ++mi)
    #pragma unroll
    for (int ni = 0; ni < 4; ++ni) {
      int col = n0 + nb + ni * 16 + r;
      #pragma unroll
      for (int i = 0; i < 4; ++i) {
        int row = m0 + mb + mi * 16 + q * 4 + i;
        store_out(mode, relu, scale, bias, bias2, bias3,
                  outF, outB, N, row, col, acc[mi][ni][i]);
      }
    }
}

// ------------------- GEMM 256^2, 8-wave, counted-vmcnt ---------------------
// BK=32, ring of FOUR DISTINCT LDS K-tile buffers (compile-time objects so
// SIInsertWaitcnts' LDS-DMA tracking stays precise -- round-1/2 lesson).
// Per tile: vmcnt(8) [2 tiles in flight, NEVER 0 in steady state] -> barrier
// -> stage tile t+3 into slot (t+3)&3 (its previous occupant t-1 was fully
// read before this barrier) -> 12x ds_read_b128 (T2-swizzled) -> setprio(1)
// 32x MFMA setprio(0). Raw s_barrier is safe: every ds_read is consumed by
// MFMA (compiler lgkmcnt) before the wave reaches the next barrier.
// Tail: vmcnt steps 8 -> 4 -> 0. Requires K%128==0 (K=1024 here), M%256==0,
// N%256==0, gridDim.y%8==0. No sched_barrier pins anywhere (m131-m141).
__global__ __launch_bounds__(512) void gemm256(
    const bf16_t* __restrict__ A, const bf16_t* __restrict__ Bt,
    const float* __restrict__ bias, const float* __restrict__ bias2,
    const float* __restrict__ bias3,
    float* outF, bf16_t* outB,
    int M, int N, int K, int mode, int relu, float scale)
{
  __shared__ __attribute__((aligned(16))) bf16_t A0ls[256 * 32];
  __shared__ __attribute__((aligned(16))) bf16_t A1ls[256 * 32];
  __shared__ __attribute__((aligned(16))) bf16_t A2ls[256 * 32];
  __shared__ __attribute__((aligned(16))) bf16_t A3ls[256 * 32];
  __shared__ __attribute__((aligned(16))) bf16_t B0ls[256 * 32];
  __shared__ __attribute__((aligned(16))) bf16_t B1ls[256 * 32];
  __shared__ __attribute__((aligned(16))) bf16_t B2ls[256 * 32];
  __shared__ __attribute__((aligned(16))) bf16_t B3ls[256 * 32];

  const int tid  = threadIdx.x;          // 0..511
  const int lane = tid & 63;
  const int w    = tid >> 6;             // 0..7
  const int wm   = w >> 2;               // 0..1 (M split)
  const int wn   = w & 3;                // 0..3 (N split)
  const int q    = lane >> 4;
  const int r    = lane & 15;

  // XCD-aware block swizzle (gy = M/256 = 32, multiple of 8)
  const int gx = gridDim.x;
  const int b  = blockIdx.y * gx + blockIdx.x;
  const int t_ = b >> 3;
  const int bm = (t_ / gx) * 8 + (b & 7);
  const int bn = t_ % gx;
  const int m0 = bm * 256;
  const int n0 = bn * 256;

  const int qs = (q ^ ((r >> 1) & 3)) * 8;   // swizzled 16B read slot
  const int T  = K >> 5;                     // BK=32 tiles

  f32x4 acc[8][4] = {};

#define STG256(AD, BD, kt) do {                                               \
    int kb = (kt) << 5;                                                       \
    _Pragma("unroll")                                                         \
    for (int ld = 0; ld < 2; ++ld) {                                          \
      int s   = ld * 512 + tid;                                               \
      int row = s >> 2;                                                       \
      int c8  = (((s & 3) ^ ((s >> 3) & 3)) << 3);                            \
      gl_lds16(A  + (size_t)(m0 + row) * K + kb + c8, &AD[s * 8]);            \
      gl_lds16(Bt + (size_t)(n0 + row) * K + kb + c8, &BD[s * 8]);            \
    }                                                                         \
  } while (0)

#define BODY256(tt, AR, BR, AS, BS) do {                                      \
    if ((tt) <= T - 3)      asm volatile("s_waitcnt vmcnt(8)");               \
    else if ((tt) == T - 2) asm volatile("s_waitcnt vmcnt(4)");               \
    else                    asm volatile("s_waitcnt vmcnt(0)");               \
    __builtin_amdgcn_s_barrier();                                             \
    if ((tt) + 3 < T) STG256(AS, BS, (tt) + 3);                               \
    bf16x8 af[8], bfr[4];                                                     \
    _Pragma("unroll")                                                         \
    for (int fm = 0; fm < 8; ++fm)                                            \
      af[fm] = *(const bf16x8*)&AR[(wm * 128 + fm * 16 + r) * 32 + qs];       \
    _Pragma("unroll")                                                         \
    for (int fn = 0; fn < 4; ++fn)                                            \
      bfr[fn] = *(const bf16x8*)&BR[(wn * 64 + fn * 16 + r) * 32 + qs];       \
    __builtin_amdgcn_s_setprio(1);                                            \
    _Pragma("unroll")                                                         \
    for (int fm = 0; fm < 8; ++fm)                                            \
      _Pragma("unroll")                                                       \
      for (int fn = 0; fn < 4; ++fn)                                          \
        acc[fm][fn] = MFMA_BF16(af[fm], bfr[fn], acc[fm][fn]);                \
    __builtin_amdgcn_s_setprio(0);                                            \
  } while (0)

  // prologue: 3 tiles in flight (12 loads/thread)
  STG256(A0ls, B0ls, 0);
  STG256(A1ls, B1ls, 1);
  STG256(A2ls, B2ls, 2);

  for (int t = 0; t < T; t += 4) {
    BODY256(t + 0, A0ls, B0ls, A3ls, B3ls);
    BODY256(t + 1, A1ls, B1ls, A0ls, B0ls);
    BODY256(t + 2, A2ls, B2ls, A1ls, B1ls);
    BODY256(t + 3, A3ls, B3ls, A2ls, B2ls);
  }
#undef STG256
#undef BODY256

  #pragma unroll
  for (int fm = 0; fm < 8; ++fm)
    #pragma unroll
    for (int fn = 0; fn < 4; ++fn) {
      int col = n0 + wn * 64 + fn * 16 + r;
      #pragma unroll
      for (int i = 0; i < 4; ++i) {
        int row = m0 + wm * 128 + fm * 16 + q * 4 + i;
        store_out(mode, relu, scale, bias, bias2, bias3,
                  outF, outB, N, row, col, acc[fm][fn][i]);
      }
    }
}

// --------------------------- flash attention -------------------------------
// m97 2-barrier form -- rounds 1-2 proved source-level pipelining here loses
// (125.6/120.4 vs 112 us). Keep simple.
__global__ __launch_bounds__(256) void flash_attn(
    const bf16_t* __restrict__ Q, const bf16_t* __restrict__ Kb,
    const bf16_t* __restrict__ Vt, bf16_t* __restrict__ O)
{
  __shared__ __attribute__((aligned(16))) bf16_t Kls[64 * 64];
  __shared__ __attribute__((aligned(16))) bf16_t Vls[64 * 64];

  const int tid  = threadIdx.x;
  const int w    = tid >> 6;
  const int lane = tid & 63;
  const int q    = lane >> 4;
  const int r    = lane & 15;

  const int bl   = blockIdx.y * gridDim.x + blockIdx.x;
  const int bh   = (bl & 7) * 8 + ((bl >> 3) & 7);
  const int q0   = (bl >> 6) * 128 + w * 32;

  const bf16_t* Qp  = Q  + ((size_t)bh * SEQ_ + q0) * DK_;
  const bf16_t* Kp0 = Kb + (size_t)bh * SEQ_ * DK_;
  const bf16_t* Vp0 = Vt + (size_t)bh * DK_ * SEQ_;

  bf16x8 aq[2][2];
  #pragma unroll
  for (int rt = 0; rt < 2; ++rt)
    #pragma unroll
    for (int c = 0; c < 2; ++c)
      aq[rt][c] = *(const bf16x8*)(Qp + (rt * 16 + r) * DK_ + 32 * c + 8 * q);

  f32x4 o[2][4] = {};
  f32x4 l4[2] = {};

  const int srow0 = tid >> 3;
  const int scol0 = ((tid & 7) ^ (srow0 & 7)) * 8;
  const int srow1 = srow0 + 32;
  const int scol1 = ((tid & 7) ^ (srow1 & 7)) * 8;
  const int r7 = r & 7;

  for (int kv = 0; kv < SEQ_; kv += 64) {
    gl_lds16(Kp0 + (size_t)(kv + srow0) * DK_ + scol0, Kls + tid * 8);
    gl_lds16(Kp0 + (size_t)(kv + srow1) * DK_ + scol1, Kls + 2048 + tid * 8);
    gl_lds16(Vp0 + (size_t)srow0 * SEQ_ + kv + scol0, Vls + tid * 8);
    gl_lds16(Vp0 + (size_t)srow1 * SEQ_ + kv + scol1, Vls + 2048 + tid * 8);
    __syncthreads();

    bf16x8 kf[4][2];
    #pragma unroll
    for (int mt = 0; mt < 4; ++mt)
      #pragma unroll
      for (int c = 0; c < 2; ++c)
        kf[mt][c] = *(const bf16x8*)&Kls[(((16 * mt + r) * 8) + ((4 * c + q) ^ r7)) * 8];
    s16x4 vf[4][4];
    #pragma unroll
    for (int dt = 0; dt < 4; ++dt)
      #pragma unroll
      for (int mt = 0; mt < 4; ++mt)
        vf[dt][mt] = *(const s16x4*)&Vls[(((16 * dt + r) * 8) +
                        ((2 * mt + (q >> 1)) ^ r7)) * 8 + (q & 1) * 4];

    #pragma unroll
    for (int rt = 0; rt < 2; ++rt) {
      f32x4 st[4] = {};
      #pragma unroll
      for (int mt = 0; mt < 4; ++mt) {
        st[mt] = MFMA_BF16(kf[mt][0], aq[rt][0], st[mt]);
        st[mt] = MFMA_BF16(kf[mt][1], aq[rt][1], st[mt]);
      }
      s16x4 pf[4];
      f32x4 psum = {};
      #pragma unroll
      for (int mt = 0; mt < 4; ++mt) {
        f32x4 pe;
        #pragma unroll
        for (int i = 0; i < 4; ++i) pe[i] = fast_exp2(st[mt][i]);
        psum += pe;
        bf16x4 pb;
        #pragma unroll
        for (int i = 0; i < 4; ++i) pb[i] = (bf16_t)pe[i];
        pf[mt] = __builtin_bit_cast(s16x4, pb);
      }
      l4[rt] += psum;
      #pragma unroll
      for (int dt = 0; dt < 4; ++dt)
        #pragma unroll
        for (int mt = 0; mt < 4; ++mt)
          o[rt][dt] = MFMA16(vf[dt][mt], pf[mt], o[rt][dt]);
    }
    __syncthreads();
  }

  const int b = bh >> 4, h = bh & 15;
  #pragma unroll
  for (int rt = 0; rt < 2; ++rt) {
    float lr = (l4[rt][0] + l4[rt][1]) + (l4[rt][2] + l4[rt][3]);
    lr += __shfl_xor(lr, 16);
    lr += __shfl_xor(lr, 32);
    float linv = 1.f / lr;
    int token = b * SEQ_ + q0 + rt * 16 + r;
    #pragma unroll
    for (int dt = 0; dt < 4; ++dt) {
      bf16x4 ob;
      #pragma unroll
      for (int i = 0; i < 4; ++i) ob[i] = (bf16_t)(o[rt][dt][i] * linv);
      *(bf16x4*)(O + (size_t)token * DM_ + h * DK_ + 16 * dt + 4 * q) = ob;
    }
  }
}

// ------------------------- residual + layernorm ----------------------------
__global__ __launch_bounds__(256) void resid_ln(
    const float* A, const float* Bv, const float* Cv,
    const float* g, const float* be,
    float* outF, bf16_t* outB)
{
  const int w = threadIdx.x >> 6, lane = threadIdx.x & 63;
  const int row = blockIdx.x * 4 + w;
  const float* a = A  + (size_t)row * DM_;
  const float* b = Bv + (size_t)row * DM_;
  const float* c3 = Cv ? Cv + (size_t)row * DM_ : nullptr;
  float v[16];
  float s = 0.f;
  #pragma unroll
  for (int c = 0; c < 4; ++c) {
    f32x4 x = *(const f32x4*)(a + c * 256 + lane * 4);
    f32x4 y = *(const f32x4*)(b + c * 256 + lane * 4);
    f32x4 z = {};
    if (c3) z = *(const f32x4*)(c3 + c * 256 + lane * 4);
    #pragma unroll
    for (int k = 0; k < 4; ++k) {
      v[c * 4 + k] = x[k] + y[k] + z[k];
      s += v[c * 4 + k];
    }
  }
  s += __shfl_xor(s, 1);  s += __shfl_xor(s, 2);  s += __shfl_xor(s, 4);
  s += __shfl_xor(s, 8);  s += __shfl_xor(s, 16); s += __shfl_xor(s, 32);
  float mu = s * (1.f / DM_);
  float ss = 0.f;
  #pragma unroll
  for (int k = 0; k < 16; ++k) { float d = v[k] - mu; ss += d * d; }
  ss += __shfl_xor(ss, 1);  ss += __shfl_xor(ss, 2);  ss += __shfl_xor(ss, 4);
  ss += __shfl_xor(ss, 8);  ss += __shfl_xor(ss, 16); ss += __shfl_xor(ss, 32);
  float rstd = rsqrtf(ss * (1.f / DM_) + 1e-5f);
  #pragma unroll
  for (int c = 0; c < 4; ++c) {
    int idx = c * 256 + lane * 4;
    f32x4 gg = *(const f32x4*)(g + idx);
    f32x4 bb = *(const f32x4*)(be + idx);
    f32x4 ov; bf16x4 ob;
    #pragma unroll
    for (int k = 0; k < 4; ++k) {
      float val = (v[c * 4 + k] - mu) * rstd * gg[k] + bb[k];
      ov[k] = val; ob[k] = (bf16_t)val;
    }
    *(f32x4*)(outF + (size_t)row * DM_ + idx) = ov;
    if (outB) *(bf16x4*)(outB + (size_t)row * DM_ + idx) = ob;
  }
}

// ---------------------------------------------------------------------------
extern "C" void kernel_launch(void* const* d_in, const int* in_sizes, int n_in,
                              void* d_out, int out_size, void* d_ws, size_t ws_size,
                              hipStream_t stream)
{
  (void)in_sizes; (void)n_in; (void)out_size; (void)ws_size;
  const float* src   = (const float*)d_in[0];
  const float* tgt   = (const float*)d_in[1];
  const float* sa_wq = (const float*)d_in[2];  const float* sa_bq = (const float*)d_in[3];
  const float* sa_wk = (const float*)d_in[4];  const float* sa_bk = (const float*)d_in[5];
  const float* sa_wv = (const float*)d_in[6];  const float* sa_bv = (const float*)d_in[7];
  const float* sa_wo = (const float*)d_in[8];  const float* sa_bo = (const float*)d_in[9];
  const float* ca_wq = (const float*)d_in[10]; const float* ca_bq = (const float*)d_in[11];
  const float* ca_wk = (const float*)d_in[12]; const float* ca_bk = (const float*)d_in[13];
  const float* ca_wv = (const float*)d_in[14]; const float* ca_bv = (const float*)d_in[15];
  const float* ca_wo = (const float*)d_in[16]; const float* ca_bo = (const float*)d_in[17];
  const float* ff_w1 = (const float*)d_in[18]; const float* ff_b1 = (const float*)d_in[19];
  const float* ff_w2 = (const float*)d_in[20]; const float* ff_b2 = (const float*)d_in[21];
  const float* ln1g  = (const float*)d_in[22]; const float* ln1b  = (const float*)d_in[23];
  const float* ln2g  = (const float*)d_in[24]; const float* ln2b  = (const float*)d_in[25];
  const float* ln3g  = (const float*)d_in[26]; const float* ln3b  = (const float*)d_in[27];

  char* p = (char*)d_ws;
  auto alloc = [&](size_t bytes) -> char* {
    char* r = p; p += (bytes + 255) & ~(size_t)255; return r;
  };

  const size_t ACT_B  = (size_t)TOK_ * DM_ * 2;
  const size_t W_B    = (size_t)DM_ * DM_ * 2;
  const size_t HEAD_B = HEADEL_ * 2;

  bf16_t* tgt_bf = (bf16_t*)alloc(ACT_B);
  bf16_t* src_bf = (bf16_t*)alloc(ACT_B);
  bf16_t* wt_saq = (bf16_t*)alloc(W_B);
  bf16_t* wt_sak = (bf16_t*)alloc(W_B);
  bf16_t* wt_sav = (bf16_t*)alloc(W_B);
  bf16_t* wt_sao = (bf16_t*)alloc(W_B);
  bf16_t* wt_caq = (bf16_t*)alloc(W_B);
  bf16_t* wt_cak = (bf16_t*)alloc(W_B);
  bf16_t* wt_cav = (bf16_t*)alloc(W_B);
  bf16_t* wt_cao = (bf16_t*)alloc(W_B);
  bf16_t* w1t    = (bf16_t*)alloc((size_t)DFF_ * DM_ * 2);
  bf16_t* w2t    = (bf16_t*)alloc((size_t)DM_ * DFF_ * 2);
  char*   Rg     = alloc((size_t)TOK_ * DFF_ * 2);
  bf16_t* Qb     = (bf16_t*)Rg;
  bf16_t* Kbuf   = (bf16_t*)(Rg + HEAD_B);
  bf16_t* Vtb    = (bf16_t*)(Rg + 2 * HEAD_B);
  bf16_t* attnO  = (bf16_t*)(Rg + 3 * HEAD_B);
  bf16_t* hbuf   = (bf16_t*)Rg;
  float*  x1F    = (float*)alloc((size_t)TOK_ * DM_ * 4);
  bf16_t* x1B    = (bf16_t*)alloc(ACT_B);
  float*  x2F    = (float*)alloc((size_t)TOK_ * DM_ * 4);
  bf16_t* x2B    = (bf16_t*)alloc(ACT_B);
  float*  yF     = (float*)d_out;

  const int n4 = TOK_ * DM_ / 4;
  cvt_bf16<<<n4 / 256, 256, 0, stream>>>(tgt, tgt_bf, n4);
  cvt_bf16<<<n4 / 256, 256, 0, stream>>>(src, src_bf, n4);

  dim3 tb(32, 8);
  transpose_w8<<<dim3(32, 32, 8), tb, 0, stream>>>(
      sa_wq, sa_wk, sa_wv, sa_wo, ca_wq, ca_wk, ca_wv, ca_wo, wt_saq);
  transpose_w<<<dim3(128, 32), tb, 0, stream>>>(ff_w1, w1t, DM_, DFF_);
  transpose_w<<<dim3(32, 128), tb, 0, stream>>>(ff_w2, w2t, DFF_, DM_);

  dim3 g1(DM_ / 128, TOK_ / 128);        // (8, 64)   128^2 shapes
  dim3 q3(3 * DM_ / 256, TOK_ / 256);    // (12, 32)  QKV 256^2
  dim3 q2(2 * DM_ / 256, TOK_ / 256);    // (8, 32)   CAKV 256^2
  dim3 qf(DFF_ / 256, TOK_ / 256);       // (16, 32)  FF1 256^2
  dim3 ga(SEQ_ / 128, BH_);              // (16, 64)

  // ---- self attention ----
  gemm256<<<q3, 512, 0, stream>>>(tgt_bf, wt_saq, sa_bq, sa_bk, sa_bv,
                                  nullptr, Qb, TOK_, 3 * DM_, DM_, 3, 0, QSCALE_);
  flash_attn<<<ga, 256, 0, stream>>>(Qb, Kbuf, Vtb, attnO);
  gemm_bf16<<<g1, 256, 0, stream>>>(attnO, wt_sao, sa_bo, nullptr, nullptr,
                                    yF, nullptr, TOK_, DM_, DM_, 0, 0, 1.f);
  resid_ln<<<TOK_ / 4, 256, 0, stream>>>(tgt, yF, nullptr, ln1g, ln1b, x1F, x1B);

  // ---- cross attention ----
  gemm_bf16<<<g1, 256, 0, stream>>>(x1B, wt_caq, ca_bq, nullptr, nullptr,
                                    nullptr, Qb, TOK_, DM_, DM_, 1, 0, QSCALE_);
  gemm256<<<q2, 512, 0, stream>>>(src_bf, wt_cak, ca_bk, ca_bv, nullptr,
                                  nullptr, Kbuf, TOK_, 2 * DM_, DM_, 4, 0, 1.f);
  flash_attn<<<ga, 256, 0, stream>>>(Qb, Kbuf, Vtb, attnO);
  gemm_bf16<<<g1, 256, 0, stream>>>(attnO, wt_cao, ca_bo, nullptr, nullptr,
                                    yF, nullptr, TOK_, DM_, DM_, 0, 0, 1.f);
  resid_ln<<<TOK_ / 4, 256, 0, stream>>>(x1F, yF, nullptr, ln2g, ln2b, x2F, x2B);

  // ---- feed forward ----
  gemm256<<<qf, 512, 0, stream>>>(x2B, w1t, ff_b1, nullptr, nullptr,
                                  nullptr, hbuf, TOK_, DFF_, DM_, 0, 1, 1.f);
  gemm_bf16<<<g1, 256, 0, stream>>>(hbuf, w2t, ff_b2, nullptr, nullptr,
                                    yF, nullptr, TOK_, DM_, DFF_, 0, 0, 1.f);
  resid_ln<<<TOK_ / 4, 256, 0, stream>>>(x2F, yF, nullptr, ln3g, ln3b,
                                         (float*)d_out, nullptr);
}

// Round 8
// 942.515 us; speedup vs baseline: 1.1095x; 1.1095x over previous
//
#include <hip/hip_runtime.h>
#include <hip/hip_bf16.h>
#include <stdint.h>

// ---------------------------------------------------------------------------
// Transformer decoder layer, bf16 MFMA pipeline.
// B=4, S=2048, D=1024, H=16, dk=64, DFF=4096, tokens=8192.
// Round 8: gemm256 (r7) DELETED -- 170us flat across shapes, MfmaUtil 12%:
// compiler interleaved gl_lds issues among ds_reads and inserted vmcnt(0)
// drains on fresh HBM loads (~6.4k cyc/tile, latency-serialized). Third
// failed sync-structure edit (r1/r2/r7) -> axis closed; all GEMMs on the
// verified 128^2 swizzled path. flash_attn: softmax denominator moved from
// VALU (psum adds + epilogue shuffles) to MFMA pipe via all-ones A-operand.
// ---------------------------------------------------------------------------

typedef __bf16 bf16_t;
typedef __bf16 bf16x8 __attribute__((ext_vector_type(8)));
typedef __bf16 bf16x4 __attribute__((ext_vector_type(4)));
typedef float  f32x4  __attribute__((ext_vector_type(4)));
typedef short  s16x4  __attribute__((ext_vector_type(4)));

#define SEQ_    2048
#define BATCH_  4
#define DM_     1024
#define NH_     16
#define DK_     64
#define DFF_    4096
#define TOK_    (BATCH_*SEQ_)     // 8192
#define BH_     (BATCH_*NH_)      // 64
#define HEADEL_ ((size_t)BH_*SEQ_*DK_)   // elements per head tensor

// 1/sqrt(dk) * log2(e): fold attention scale + exp->exp2 into Q projection
#define QSCALE_ 0.18033688011112042f

#define MFMA_BF16(a,b,c) __builtin_amdgcn_mfma_f32_16x16x32_bf16((a),(b),(c),0,0,0)
// K=16 bf16 MFMA (instruction v_mfma_f32_16x16x16_bf16)
#define MFMA16(a,b,c) __builtin_amdgcn_mfma_f32_16x16x16bf16_1k((a),(b),(c),0,0,0)

static __device__ __forceinline__ void gl_lds16(const void* g, void* l) {
  __builtin_amdgcn_global_load_lds(
      (const __attribute__((address_space(1))) uint32_t*)g,
      (__attribute__((address_space(3))) uint32_t*)l, 16, 0, 0);
}

static __device__ __forceinline__ float fast_exp2(float x) {
#if __has_builtin(__builtin_amdgcn_exp2f)
  return __builtin_amdgcn_exp2f(x);
#else
  return exp2f(x);
#endif
}

// --------------------------- f32 -> bf16 convert ---------------------------
// z-dim selects (in0->out0) or (in1->out1): one launch for tgt+src.
__global__ __launch_bounds__(256) void cvt_bf16_2(
    const float* __restrict__ in0, bf16_t* __restrict__ out0,
    const float* __restrict__ in1, bf16_t* __restrict__ out1, int n4) {
  const float* in  = blockIdx.z ? in1  : in0;
  bf16_t*      out = blockIdx.z ? out1 : out0;
  int i = blockIdx.x * 256 + threadIdx.x;
  if (i < n4) {
    f32x4 v = *(const f32x4*)(in + (size_t)i * 4);
    bf16x4 o;
    o[0] = (bf16_t)v[0]; o[1] = (bf16_t)v[1]; o[2] = (bf16_t)v[2]; o[3] = (bf16_t)v[3];
    *(bf16x4*)(out + (size_t)i * 4) = o;
  }
}

// -------------------- weight transpose: W(K,N) -> Wt(N,K) bf16 -------------
__global__ __launch_bounds__(256) void transpose_w(const float* __restrict__ W,
                                                   bf16_t* __restrict__ Wt,
                                                   int K, int N) {
  __shared__ float t[32][33];
  int bx = blockIdx.x * 32;
  int by = blockIdx.y * 32;
  int tx = threadIdx.x;
  int ty = threadIdx.y;
  #pragma unroll
  for (int i = 0; i < 32; i += 8)
    t[ty + i][tx] = W[(size_t)(by + ty + i) * N + bx + tx];
  __syncthreads();
  #pragma unroll
  for (int i = 0; i < 32; i += 8)
    Wt[(size_t)(bx + ty + i) * K + by + tx] = (bf16_t)t[tx][ty + i];
}

// ---- batched variant: 8 square DM_ x DM_ attn weights in ONE launch -------
__global__ __launch_bounds__(256) void transpose_w8(
    const float* __restrict__ w0, const float* __restrict__ w1,
    const float* __restrict__ w2, const float* __restrict__ w3,
    const float* __restrict__ w4, const float* __restrict__ w5,
    const float* __restrict__ w6, const float* __restrict__ w7,
    bf16_t* __restrict__ dst)
{
  __shared__ float t[32][33];
  const int z = blockIdx.z;
  const float* W;
  switch (z) {
    case 0: W = w0; break; case 1: W = w1; break;
    case 2: W = w2; break; case 3: W = w3; break;
    case 4: W = w4; break; case 5: W = w5; break;
    case 6: W = w6; break; default: W = w7; break;
  }
  bf16_t* Wt = dst + (size_t)z * DM_ * DM_;
  int bx = blockIdx.x * 32;
  int by = blockIdx.y * 32;
  int tx = threadIdx.x;
  int ty = threadIdx.y;
  #pragma unroll
  for (int i = 0; i < 32; i += 8)
    t[ty + i][tx] = W[(size_t)(by + ty + i) * DM_ + bx + tx];
  __syncthreads();
  #pragma unroll
  for (int i = 0; i < 32; i += 8)
    Wt[(size_t)(bx + ty + i) * DM_ + by + tx] = (bf16_t)t[tx][ty + i];
}

// ------------------------------- GEMM --------------------------------------
// 128^2 tile, 2-phase, BK=64. Verified structure (r6: 934.8us total,
// SQ_LDS_BANK_CONFLICT ~0 via the (row>>1)&3 slot-XOR; both-sides rule #21:
// linear gl_lds dest + inverse-swizzled global source + swizzled read).
// r4: split-K neutral (schedule-limited, not block-limited). r7: deep
// pipeline catastrophically latency-serialized. This IS the structure.
__global__ __launch_bounds__(256) void gemm_bf16(
    const bf16_t* __restrict__ A, const bf16_t* __restrict__ Bt,
    const float* __restrict__ bias, const float* __restrict__ bias2,
    const float* __restrict__ bias3,
    float* outF, bf16_t* outB,
    int M, int N, int K, int mode, int relu, float scale)
{
  __shared__ __attribute__((aligned(16))) bf16_t lsA[2][128 * 32];
  __shared__ __attribute__((aligned(16))) bf16_t lsB[2][128 * 32];

  const int tid  = threadIdx.x;
  const int lane = tid & 63;
  const int w    = tid >> 6;
  const int q    = lane >> 4;
  const int r    = lane & 15;

  const int gx = gridDim.x;
  const int b  = blockIdx.y * gx + blockIdx.x;
  const int t_ = b >> 3;
  const int bm = (t_ / gx) * 8 + (b & 7);
  const int bn = t_ % gx;
  const int m0 = bm * 128;
  const int n0 = bn * 128;

  const int mb   = (w >> 1) * 64;
  const int nb   = (w & 1) * 64;
  const int qs = (q ^ ((r >> 1) & 3)) * 8;

  f32x4 acc[4][4] = {};

  for (int k0 = 0; k0 < K; k0 += 64) {
    #pragma unroll
    for (int h = 0; h < 2; ++h) {
      #pragma unroll
      for (int rr = 0; rr < 2; ++rr) {
        int flat = rr * 2048 + tid * 8;
        int row  = flat >> 5;
        int col  = ((((flat >> 3) & 3) ^ ((flat >> 6) & 3)) << 3);
        gl_lds16(A  + (size_t)(m0 + row) * K + k0 + 32 * h + col, &lsA[h][flat]);
        gl_lds16(Bt + (size_t)(n0 + row) * K + k0 + 32 * h + col, &lsB[h][flat]);
      }
    }
    __syncthreads();
    #pragma unroll
    for (int h = 0; h < 2; ++h) {
      bf16x8 af[4], bfr[4];
      #pragma unroll
      for (int mi = 0; mi < 4; ++mi)
        af[mi] = *(const bf16x8*)&lsA[h][(mb + mi * 16 + r) * 32 + qs];
      #pragma unroll
      for (int ni = 0; ni < 4; ++ni)
        bfr[ni] = *(const bf16x8*)&lsB[h][(nb + ni * 16 + r) * 32 + qs];
      #pragma unroll
      for (int mi = 0; mi < 4; ++mi)
        #pragma unroll
        for (int ni = 0; ni < 4; ++ni)
          acc[mi][ni] = MFMA_BF16(af[mi], bfr[ni], acc[mi][ni]);
    }
    __syncthreads();
  }

  #pragma unroll
  for (int mi = 0; mi < 4; ++mi) {
    #pragma unroll
    for (int ni = 0; ni < 4; ++ni) {
      int col = n0 + nb + ni * 16 + r;
      float bv, sc = scale;
      int seg = 0, cw = col;
      if (mode == 3) {
        seg = col >> 10; cw = col & 1023;
        bv = (seg == 0) ? bias[cw] : ((seg == 1) ? bias2[cw] : bias3[cw]);
        if (seg != 0) sc = 1.f;
      } else if (mode == 4) {
        seg = col >> 10; cw = col & 1023;
        bv = (seg == 0) ? bias[cw] : bias2[cw];
      } else {
        bv = bias[col];
      }
      #pragma unroll
      for (int i = 0; i < 4; ++i) {
        int row = m0 + mb + mi * 16 + q * 4 + i;
        float v = (acc[mi][ni][i] + bv) * sc;
        if (relu) v = fmaxf(v, 0.f);
        if (outF) outF[(size_t)row * N + col] = v;
        if (outB) {
          size_t idx;
          if (mode == 0) {
            idx = (size_t)row * N + col;
          } else {
            int bb = row >> 11, s = row & 2047, h = cw >> 6, d = cw & 63;
            bool vt; size_t base;
            if (mode == 1)      { vt = false; base = 0; }
            else if (mode == 2) { vt = true;  base = 0; }
            else if (mode == 3) { vt = (seg == 2); base = (size_t)seg * HEADEL_; }
            else                { vt = (seg == 1); base = (size_t)seg * HEADEL_; }
            if (!vt) idx = base + ((size_t)(bb * NH_ + h) * SEQ_ + s) * DK_ + d;
            else     idx = base + ((size_t)(bb * NH_ + h) * DK_ + d) * SEQ_ + s;
          }
          outB[idx] = (bf16_t)v;
        }
      }
    }
  }
}

// --------------------------- flash attention -------------------------------
// m97 2-barrier form (rounds 1-2: pipelining attempts lose here).
// Round 8: softmax denominator l computed on the MFMA pipe instead of VALU:
// lacc[rt] = MFMA16(ones, pf[mt], lacc[rt]) -- with A = all-ones 16x16,
// C[row][col] = sum_k P^T[k][col] = l[col]; lane(q,r) holds col=r, so every
// lacc[rt][i] equals l for q-row r. Removes 40 v_add/tile (psum + l4) AND
// the two epilogue shfl_xor reduces (MFMA contracts across lanes).
// VALU was the binding pipe (VALUBusy 56% vs MfmaUtil 39%).
__global__ __launch_bounds__(256) void flash_attn(
    const bf16_t* __restrict__ Q, const bf16_t* __restrict__ Kb,
    const bf16_t* __restrict__ Vt, bf16_t* __restrict__ O)
{
  __shared__ __attribute__((aligned(16))) bf16_t Kls[64 * 64];
  __shared__ __attribute__((aligned(16))) bf16_t Vls[64 * 64];

  const int tid  = threadIdx.x;
  const int w    = tid >> 6;
  const int lane = tid & 63;
  const int q    = lane >> 4;
  const int r    = lane & 15;

  const int bl   = blockIdx.y * gridDim.x + blockIdx.x;
  const int bh   = (bl & 7) * 8 + ((bl >> 3) & 7);
  const int q0   = (bl >> 6) * 128 + w * 32;

  const bf16_t* Qp  = Q  + ((size_t)bh * SEQ_ + q0) * DK_;
  const bf16_t* Kp0 = Kb + (size_t)bh * SEQ_ * DK_;
  const bf16_t* Vp0 = Vt + (size_t)bh * DK_ * SEQ_;

  bf16x8 aq[2][2];
  #pragma unroll
  for (int rt = 0; rt < 2; ++rt)
    #pragma unroll
    for (int c = 0; c < 2; ++c)
      aq[rt][c] = *(const bf16x8*)(Qp + (rt * 16 + r) * DK_ + 32 * c + 8 * q);

  f32x4 o[2][4] = {};
  f32x4 lacc[2] = {};
  // all-ones bf16 A-fragment (1.0 = 0x3F80)
  s16x4 ones;
  ones[0] = (short)0x3F80; ones[1] = (short)0x3F80;
  ones[2] = (short)0x3F80; ones[3] = (short)0x3F80;

  const int srow0 = tid >> 3;
  const int scol0 = ((tid & 7) ^ (srow0 & 7)) * 8;
  const int srow1 = srow0 + 32;
  const int scol1 = ((tid & 7) ^ (srow1 & 7)) * 8;
  const int r7 = r & 7;

  for (int kv = 0; kv < SEQ_; kv += 64) {
    gl_lds16(Kp0 + (size_t)(kv + srow0) * DK_ + scol0, Kls + tid * 8);
    gl_lds16(Kp0 + (size_t)(kv + srow1) * DK_ + scol1, Kls + 2048 + tid * 8);
    gl_lds16(Vp0 + (size_t)srow0 * SEQ_ + kv + scol0, Vls + tid * 8);
    gl_lds16(Vp0 + (size_t)srow1 * SEQ_ + kv + scol1, Vls + 2048 + tid * 8);
    __syncthreads();

    bf16x8 kf[4][2];
    #pragma unroll
    for (int mt = 0; mt < 4; ++mt)
      #pragma unroll
      for (int c = 0; c < 2; ++c)
        kf[mt][c] = *(const bf16x8*)&Kls[(((16 * mt + r) * 8) + ((4 * c + q) ^ r7)) * 8];
    s16x4 vf[4][4];
    #pragma unroll
    for (int dt = 0; dt < 4; ++dt)
      #pragma unroll
      for (int mt = 0; mt < 4; ++mt)
        vf[dt][mt] = *(const s16x4*)&Vls[(((16 * dt + r) * 8) +
                        ((2 * mt + (q >> 1)) ^ r7)) * 8 + (q & 1) * 4];

    #pragma unroll
    for (int rt = 0; rt < 2; ++rt) {
      f32x4 st[4] = {};
      #pragma unroll
      for (int mt = 0; mt < 4; ++mt) {
        st[mt] = MFMA_BF16(kf[mt][0], aq[rt][0], st[mt]);
        st[mt] = MFMA_BF16(kf[mt][1], aq[rt][1], st[mt]);
      }
      // p = exp2(s) raw; P^T C-layout == B-operand layout of 16x16x16 MFMA
      s16x4 pf[4];
      #pragma unroll
      for (int mt = 0; mt < 4; ++mt) {
        f32x4 pe;
        #pragma unroll
        for (int i = 0; i < 4; ++i) pe[i] = fast_exp2(st[mt][i]);
        bf16x4 pb;
        #pragma unroll
        for (int i = 0; i < 4; ++i) pb[i] = (bf16_t)pe[i];
        pf[mt] = __builtin_bit_cast(s16x4, pb);
      }
      #pragma unroll
      for (int mt = 0; mt < 4; ++mt)
        lacc[rt] = MFMA16(ones, pf[mt], lacc[rt]);   // l on the MFMA pipe
      #pragma unroll
      for (int dt = 0; dt < 4; ++dt)
        #pragma unroll
        for (int mt = 0; mt < 4; ++mt)
          o[rt][dt] = MFMA16(vf[dt][mt], pf[mt], o[rt][dt]);
    }
    __syncthreads();
  }

  const int b = bh >> 4, h = bh & 15;
  #pragma unroll
  for (int rt = 0; rt < 2; ++rt) {
    float linv = 1.f / lacc[rt][0];     // all rows equal l[r]; no shuffles
    int token = b * SEQ_ + q0 + rt * 16 + r;
    #pragma unroll
    for (int dt = 0; dt < 4; ++dt) {
      bf16x4 ob;
      #pragma unroll
      for (int i = 0; i < 4; ++i) ob[i] = (bf16_t)(o[rt][dt][i] * linv);
      *(bf16x4*)(O + (size_t)token * DM_ + h * DK_ + 16 * dt + 4 * q) = ob;
    }
  }
}

// ------------------------- residual + layernorm ----------------------------
__global__ __launch_bounds__(256) void resid_ln(
    const float* A, const float* Bv, const float* Cv,
    const float* g, const float* be,
    float* outF, bf16_t* outB)
{
  const int w = threadIdx.x >> 6, lane = threadIdx.x & 63;
  const int row = blockIdx.x * 4 + w;
  const float* a = A  + (size_t)row * DM_;
  const float* b = Bv + (size_t)row * DM_;
  const float* c3 = Cv ? Cv + (size_t)row * DM_ : nullptr;
  float v[16];
  float s = 0.f;
  #pragma unroll
  for (int c = 0; c < 4; ++c) {
    f32x4 x = *(const f32x4*)(a + c * 256 + lane * 4);
    f32x4 y = *(const f32x4*)(b + c * 256 + lane * 4);
    f32x4 z = {};
    if (c3) z = *(const f32x4*)(c3 + c * 256 + lane * 4);
    #pragma unroll
    for (int k = 0; k < 4; ++k) {
      v[c * 4 + k] = x[k] + y[k] + z[k];
      s += v[c * 4 + k];
    }
  }
  s += __shfl_xor(s, 1);  s += __shfl_xor(s, 2);  s += __shfl_xor(s, 4);
  s += __shfl_xor(s, 8);  s += __shfl_xor(s, 16); s += __shfl_xor(s, 32);
  float mu = s * (1.f / DM_);
  float ss = 0.f;
  #pragma unroll
  for (int k = 0; k < 16; ++k) { float d = v[k] - mu; ss += d * d; }
  ss += __shfl_xor(ss, 1);  ss += __shfl_xor(ss, 2);  ss += __shfl_xor(ss, 4);
  ss += __shfl_xor(ss, 8);  ss += __shfl_xor(ss, 16); ss += __shfl_xor(ss, 32);
  float rstd = rsqrtf(ss * (1.f / DM_) + 1e-5f);
  #pragma unroll
  for (int c = 0; c < 4; ++c) {
    int idx = c * 256 + lane * 4;
    f32x4 gg = *(const f32x4*)(g + idx);
    f32x4 bb = *(const f32x4*)(be + idx);
    f32x4 ov; bf16x4 ob;
    #pragma unroll
    for (int k = 0; k < 4; ++k) {
      float val = (v[c * 4 + k] - mu) * rstd * gg[k] + bb[k];
      ov[k] = val; ob[k] = (bf16_t)val;
    }
    *(f32x4*)(outF + (size_t)row * DM_ + idx) = ov;
    if (outB) *(bf16x4*)(outB + (size_t)row * DM_ + idx) = ob;
  }
}

// ---------------------------------------------------------------------------
extern "C" void kernel_launch(void* const* d_in, const int* in_sizes, int n_in,
                              void* d_out, int out_size, void* d_ws, size_t ws_size,
                              hipStream_t stream)
{
  (void)in_sizes; (void)n_in; (void)out_size; (void)ws_size;
  const float* src   = (const float*)d_in[0];
  const float* tgt   = (const float*)d_in[1];
  const float* sa_wq = (const float*)d_in[2];  const float* sa_bq = (const float*)d_in[3];
  const float* sa_wk = (const float*)d_in[4];  const float* sa_bk = (const float*)d_in[5];
  const float* sa_wv = (const float*)d_in[6];  const float* sa_bv = (const float*)d_in[7];
  const float* sa_wo = (const float*)d_in[8];  const float* sa_bo = (const float*)d_in[9];
  const float* ca_wq = (const float*)d_in[10]; const float* ca_bq = (const float*)d_in[11];
  const float* ca_wk = (const float*)d_in[12]; const float* ca_bk = (const float*)d_in[13];
  const float* ca_wv = (const float*)d_in[14]; const float* ca_bv = (const float*)d_in[15];
  const float* ca_wo = (const float*)d_in[16]; const float* ca_bo = (const float*)d_in[17];
  const float* ff_w1 = (const float*)d_in[18]; const float* ff_b1 = (const float*)d_in[19];
  const float* ff_w2 = (const float*)d_in[20]; const float* ff_b2 = (const float*)d_in[21];
  const float* ln1g  = (const float*)d_in[22]; const float* ln1b  = (const float*)d_in[23];
  const float* ln2g  = (const float*)d_in[24]; const float* ln2b  = (const float*)d_in[25];
  const float* ln3g  = (const float*)d_in[26]; const float* ln3b  = (const float*)d_in[27];

  char* p = (char*)d_ws;
  auto alloc = [&](size_t bytes) -> char* {
    char* r = p; p += (bytes + 255) & ~(size_t)255; return r;
  };

  const size_t ACT_B  = (size_t)TOK_ * DM_ * 2;
  const size_t W_B    = (size_t)DM_ * DM_ * 2;
  const size_t HEAD_B = HEADEL_ * 2;

  bf16_t* tgt_bf = (bf16_t*)alloc(ACT_B);
  bf16_t* src_bf = (bf16_t*)alloc(ACT_B);
  bf16_t* wt_saq = (bf16_t*)alloc(W_B);
  bf16_t* wt_sak = (bf16_t*)alloc(W_B);
  bf16_t* wt_sav = (bf16_t*)alloc(W_B);
  bf16_t* wt_sao = (bf16_t*)alloc(W_B);
  bf16_t* wt_caq = (bf16_t*)alloc(W_B);
  bf16_t* wt_cak = (bf16_t*)alloc(W_B);
  bf16_t* wt_cav = (bf16_t*)alloc(W_B);
  bf16_t* wt_cao = (bf16_t*)alloc(W_B);
  bf16_t* w1t    = (bf16_t*)alloc((size_t)DFF_ * DM_ * 2);
  bf16_t* w2t    = (bf16_t*)alloc((size_t)DM_ * DFF_ * 2);
  char*   Rg     = alloc((size_t)TOK_ * DFF_ * 2);
  bf16_t* Qb     = (bf16_t*)Rg;
  bf16_t* Kbuf   = (bf16_t*)(Rg + HEAD_B);
  bf16_t* Vtb    = (bf16_t*)(Rg + 2 * HEAD_B);
  bf16_t* attnO  = (bf16_t*)(Rg + 3 * HEAD_B);
  bf16_t* hbuf   = (bf16_t*)Rg;
  float*  x1F    = (float*)alloc((size_t)TOK_ * DM_ * 4);
  bf16_t* x1B    = (bf16_t*)alloc(ACT_B);
  float*  x2F    = (float*)alloc((size_t)TOK_ * DM_ * 4);
  bf16_t* x2B    = (bf16_t*)alloc(ACT_B);
  float*  yF     = (float*)d_out;

  const int n4 = TOK_ * DM_ / 4;
  cvt_bf16_2<<<dim3(n4 / 256, 1, 2), 256, 0, stream>>>(tgt, tgt_bf, src, src_bf, n4);

  dim3 tb(32, 8);
  transpose_w8<<<dim3(32, 32, 8), tb, 0, stream>>>(
      sa_wq, sa_wk, sa_wv, sa_wo, ca_wq, ca_wk, ca_wv, ca_wo, wt_saq);
  transpose_w<<<dim3(128, 32), tb, 0, stream>>>(ff_w1, w1t, DM_, DFF_);
  transpose_w<<<dim3(32, 128), tb, 0, stream>>>(ff_w2, w2t, DFF_, DM_);

  dim3 g1(DM_ / 128, TOK_ / 128);      // (8, 64)
  dim3 g3(3 * DM_ / 128, TOK_ / 128);  // (24, 64) fused QKV
  dim3 g2(2 * DM_ / 128, TOK_ / 128);  // (16, 64) fused KV
  dim3 gf(DFF_ / 128, TOK_ / 128);     // (32, 64)
  dim3 ga(SEQ_ / 128, BH_);            // (16, 64)

  // ---- self attention ----
  gemm_bf16<<<g3, 256, 0, stream>>>(tgt_bf, wt_saq, sa_bq, sa_bk, sa_bv,
                                    nullptr, Qb, TOK_, 3 * DM_, DM_, 3, 0, QSCALE_);
  flash_attn<<<ga, 256, 0, stream>>>(Qb, Kbuf, Vtb, attnO);
  gemm_bf16<<<g1, 256, 0, stream>>>(attnO, wt_sao, sa_bo, nullptr, nullptr,
                                    yF, nullptr, TOK_, DM_, DM_, 0, 0, 1.f);
  resid_ln<<<TOK_ / 4, 256, 0, stream>>>(tgt, yF, nullptr, ln1g, ln1b, x1F, x1B);

  // ---- cross attention ----
  gemm_bf16<<<g1, 256, 0, stream>>>(x1B, wt_caq, ca_bq, nullptr, nullptr,
                                    nullptr, Qb, TOK_, DM_, DM_, 1, 0, QSCALE_);
  gemm_bf16<<<g2, 256, 0, stream>>>(src_bf, wt_cak, ca_bk, ca_bv, nullptr,
                                    nullptr, Kbuf, TOK_, 2 * DM_, DM_, 4, 0, 1.f);
  flash_attn<<<ga, 256, 0, stream>>>(Qb, Kbuf, Vtb, attnO);
  gemm_bf16<<<g1, 256, 0, stream>>>(attnO, wt_cao, ca_bo, nullptr, nullptr,
                                    yF, nullptr, TOK_, DM_, DM_, 0, 0, 1.f);
  resid_ln<<<TOK_ / 4, 256, 0, stream>>>(x1F, yF, nullptr, ln2g, ln2b, x2F, x2B);

  // ---- feed forward ----
  gemm_bf16<<<gf, 256, 0, stream>>>(x2B, w1t, ff_b1, nullptr, nullptr,
                                    nullptr, hbuf, TOK_, DFF_, DM_, 0, 1, 1.f);
  gemm_bf16<<<g1, 256, 0, stream>>>(hbuf, w2t, ff_b2, nullptr, nullptr,
                                    yF, nullptr, TOK_, DM_, DFF_, 0, 0, 1.f);
  resid_ln<<<TOK_ / 4, 256, 0, stream>>>(x2F, yF, nullptr, ln3g, ln3b,
                                         (float*)d_out, nullptr);
}